// Round 10
// baseline (35.133 us; speedup 1.0000x reference)
//
#include <hip/hip_runtime.h>
#include <stdint.h>
#include <math.h>

#define BN 16
#define LATN 64
#define STATSN 7
#define ZN 71
#define HN 128
#define H2N 256
#define NNODE 256
#define NPAIR 32640            // N*(N-1)/2
#define NQ 522240              // BN*NPAIR
#define NT 1024                // logits block size (16 waves)

// Raw barrier: drain LDS only (lgkmcnt); leave global prefetches in flight.
#define BARRIER() asm volatile("s_waitcnt lgkmcnt(0)\n\ts_barrier" ::: "memory")

// ---------------- Threefry-2x32, 20 rounds, key = (0, 42) ----------------
__device__ __forceinline__ void tf2x32(uint32_t x0, uint32_t x1,
                                       uint32_t& o0, uint32_t& o1) {
    const uint32_t ks0 = 0u, ks1 = 42u, ks2 = 0x1BD11BF0u;  // 0^42^0x1BD11BDA
    x0 += ks0; x1 += ks1;
#define TFRND(r) { x0 += x1; x1 = (x1 << (r)) | (x1 >> (32 - (r))); x1 ^= x0; }
    TFRND(13) TFRND(15) TFRND(26) TFRND(6)
    x0 += ks1; x1 += ks2 + 1u;
    TFRND(17) TFRND(29) TFRND(16) TFRND(24)
    x0 += ks2; x1 += ks0 + 2u;
    TFRND(13) TFRND(15) TFRND(26) TFRND(6)
    x0 += ks0; x1 += ks1 + 3u;
    TFRND(17) TFRND(29) TFRND(16) TFRND(24)
    x0 += ks1; x1 += ks2 + 4u;
    TFRND(13) TFRND(15) TFRND(26) TFRND(6)
    x0 += ks2; x1 += ks0 + 5u;
#undef TFRND
    o0 = x0; o1 = x1;
}

__device__ __forceinline__ uint32_t bits_partitionable(uint32_t m) {
    uint32_t o0, o1;
    tf2x32(0u, m, o0, o1);
    return o0 ^ o1;
}

__device__ __forceinline__ float bits_to_u(uint32_t w) {
    float f = __uint_as_float((w >> 9) | 0x3f800000u) - 1.0f;
    const float mn = 1e-9f;
    return fmaxf(mn, f * (1.0f - mn) + mn);
}

// ---------------- touch-prefetch: warm L2, then discard ----------------
// issue(): N4 coalesced float4 loads; sink(): asm-consume (forces completion,
// pins issue point; values dead afterwards). Data then lives in the XCD L2.
template<int N4>
struct Touch {
    float4 v[N4];
    __device__ __forceinline__ void issue(const float* __restrict__ W, int t) {
#pragma unroll
        for (int i = 0; i < N4; ++i)
            v[i] = *reinterpret_cast<const float4*>(W + 4 * (t + i * NT));
    }
    __device__ __forceinline__ void sink() {
#pragma unroll
        for (int i = 0; i < N4; ++i)
            asm volatile("" :: "v"(v[i].x), "v"(v[i].y), "v"(v[i].z), "v"(v[i].w));
    }
};

// ---------------- at-use dot (r9-identical indices, pairing, order) ---------
template<int K, int O>
__device__ __forceinline__ double dotg(const float* __restrict__ W,
                                       const float* __restrict__ vin, int t) {
    constexpr int C = NT / O;
    constexpr int KC = (K + C - 1) / C;
    constexpr int LOGO = (O == 256) ? 8 : 7;
    const int out = t & (O - 1);
    const int k0 = (t >> LOGO) * KC;
    double a0 = 0.0, a1 = 0.0;
#pragma unroll
    for (int i = 0; i < KC; i += 2) {
        if ((K % C == 0) || (k0 + i < K))
            a0 = fma((double)vin[k0 + i], (double)W[(k0 + i) * O + out], a0);
        if ((i + 1 < KC) && ((K % C == 0) || (k0 + i + 1 < K)))
            a1 = fma((double)vin[k0 + i + 1], (double)W[(k0 + i + 1) * O + out], a1);
    }
    return a0 + a1;
}

template<int K, int O>
__device__ __forceinline__ double dotg_mask127(const float* __restrict__ W,
                                               const float* __restrict__ vin, int t) {
    constexpr int C = NT / O;
    constexpr int KC = (K + C - 1) / C;
    constexpr int LOGO = (O == 256) ? 8 : 7;
    const int out = t & (O - 1);
    const int k0 = (t >> LOGO) * KC;
    double a0 = 0.0, a1 = 0.0;
#pragma unroll
    for (int i = 0; i < KC; i += 2) {
        a0 = fma((double)vin[(k0 + i) & 127], (double)W[(k0 + i) * O + out], a0);
        if (i + 1 < KC)
            a1 = fma((double)vin[(k0 + i + 1) & 127], (double)W[(k0 + i + 1) * O + out], a1);
    }
    return a0 + a1;
}

// wave0 LN stats: butterfly; rsqrt = f32 seed + 2 f64 Newton steps (r8-verified)
template<int NV>
__device__ __forceinline__ void w0_stats(const float* v, double& m, double& rs) {
    double a = 0.0, q = 0.0;
#pragma unroll
    for (int i = 0; i < NV; ++i) {
        a += (double)v[i];
        q += (double)v[i] * (double)v[i];
    }
#pragma unroll
    for (int s = 1; s < 64; s <<= 1) {
        a += __shfl_xor(a, s, 64);
        q += __shfl_xor(q, s, 64);
    }
    constexpr double O = (double)(NV * 64);
    m = a * (1.0 / O);
    const double d = q * (1.0 / O) - m * m + 1e-5;
    double r = (double)rsqrtf((float)d);
    r = r * (1.5 - 0.5 * d * r * r);
    r = r * (1.5 - 0.5 * d * r * r);
    rs = r;
}

// epilogue-parameter LDS layout (floats)
#define P_IPB   0
#define P_IPG   256
#define P_IPBB  512
#define P_DRB   768
#define P_DRG   896
#define P_DRBB  1024
#define P_R1B   1152   /* 256: both layers */
#define P_N1G   1408
#define P_N1B   1664
#define P_N2G   1920
#define P_N2B   2176
#define P_R2B   2432
#define P_E1B   2688
#define P_EG    2816
#define P_EB    2944
#define P_E2W   3072   /* 256 */
#define P_E2B   3328   /* 2 */
#define P_SIZE  3332

__global__ __launch_bounds__(NT, 1) void logits_kernel(
    const float* __restrict__ x, const float* __restrict__ st,
    const float* __restrict__ ipw, const float* __restrict__ ipb,
    const float* __restrict__ ipg, const float* __restrict__ ipbb,
    const float* __restrict__ drw, const float* __restrict__ drb,
    const float* __restrict__ drg, const float* __restrict__ drbb,
    const float* __restrict__ r1w, const float* __restrict__ r1b,
    const float* __restrict__ r2w, const float* __restrict__ r2b,
    const float* __restrict__ n1g, const float* __restrict__ n1b,
    const float* __restrict__ n2g, const float* __restrict__ n2b,
    const float* __restrict__ e1w, const float* __restrict__ e1b,
    const float* __restrict__ eg,  const float* __restrict__ eb,
    const float* __restrict__ e2w, const float* __restrict__ e2b,
    float* __restrict__ out_logits)
{
    __shared__ __align__(16) float V0[H2N];
    __shared__ __align__(16) float V1[H2N];
    __shared__ double dpart[NT];
    __shared__ float P[P_SIZE];
    const int t = threadIdx.x;
    const int b = blockIdx.x;
    const int l = t & 63;
    const bool w0 = (t < 64);

    Touch<8> t_dr, t_e1;
    Touch<4> t_r1a, t_r2a, t_r1b, t_r2b;

    // -------- S0: params -> LDS, z -> V0, touch dr+r1a --------
    t_dr.issue(drw, t);
    t_r1a.issue(r1w, t);
    if (t < 256) {
        P[P_IPB + t] = ipb[t];  P[P_IPG + t] = ipg[t];  P[P_IPBB + t] = ipbb[t];
        P[P_R1B + t] = r1b[t];  P[P_N1G + t] = n1g[t];  P[P_N1B + t] = n1b[t];
        P[P_N2G + t] = n2g[t];  P[P_N2B + t] = n2b[t];  P[P_R2B + t] = r2b[t];
        P[P_E2W + t] = e2w[t];
    } else if (t < 384) {
        const int i = t - 256;
        P[P_DRB + i] = drb[i];  P[P_DRG + i] = drg[i];  P[P_DRBB + i] = drbb[i];
        P[P_E1B + i] = e1b[i];  P[P_EG + i] = eg[i];    P[P_EB + i] = eb[i];
    } else if (t < 386) {
        P[P_E2B + (t - 384)] = e2b[t - 384];
    }
    if (t < LATN)      V0[t] = x[b * LATN + t];
    else if (t < ZN)   V0[t] = st[b * STATSN + (t - LATN)];
    else if (t < H2N)  V0[t] = 0.0f;     // zero-pad (r9-identical)
    BARRIER();                                     // B0

    float h0 = 0.0f, h1 = 0.0f;   // running h, wave0 regs only

    // -------- S1: ip dot --------
    dpart[t] = dotg<ZN, H2N>(ipw, V0, t);
    t_r2a.issue(r2w, t);
    BARRIER();                                     // B1

    // -------- S2: ip epilogue -> V1 --------
    if (w0) {
        float v[4];
#pragma unroll
        for (int i = 0; i < 4; ++i) {
            const int o = l + 64 * i;
            double ca = 0.0;
#pragma unroll
            for (int cc = 0; cc < 4; ++cc) ca += dpart[o + cc * H2N];
            v[i] = fmaxf((float)ca + P[P_IPB + o], 0.0f);
        }
        double m, rs; w0_stats<4>(v, m, rs);
#pragma unroll
        for (int i = 0; i < 4; ++i) {
            const int o = l + 64 * i;
            V1[o] = (float)(((double)v[i] - m) * rs) * P[P_IPG + o] + P[P_IPBB + o];
        }
    }
    t_dr.sink();
    t_r1a.sink();
    BARRIER();                                     // B2

    // -------- S3: dr dot --------
    dpart[t] = dotg<H2N, HN>(drw, V1, t);
    t_r1b.issue(r1w + HN * HN, t);
    t_r2a.sink();
    BARRIER();                                     // B3

    // -------- S4: dr epilogue -> h (regs); fused LN1a -> V1 --------
    if (w0) {
        float v[2];
#pragma unroll
        for (int i = 0; i < 2; ++i) {
            const int o = l + 64 * i;
            double ca = 0.0;
#pragma unroll
            for (int cc = 0; cc < 8; ++cc) ca += dpart[o + cc * HN];
            v[i] = fmaxf((float)ca + P[P_DRB + o], 0.0f);
        }
        double m, rs; w0_stats<2>(v, m, rs);
        h0 = (float)(((double)v[0] - m) * rs) * P[P_DRG + l] + P[P_DRBB + l];
        h1 = (float)(((double)v[1] - m) * rs) * P[P_DRG + l + 64] + P[P_DRBB + l + 64];
        float hv[2] = {h0, h1};
        double m1, rs1; w0_stats<2>(hv, m1, rs1);  // LN1a fused
        V1[l]      = (float)(((double)h0 - m1) * rs1) * P[P_N1G + l] + P[P_N1B + l];
        V1[l + 64] = (float)(((double)h1 - m1) * rs1) * P[P_N1G + l + 64] + P[P_N1B + l + 64];
    }
    BARRIER();                                     // B4

    // -------- S5: res0 lin1 dot --------
    dpart[t] = dotg<HN, HN>(r1w, V1, t);
    t_r2b.issue(r2w + HN * HN, t);
    t_r1b.sink();
    BARRIER();                                     // B5

    // -------- S6: res0 lin1 epilogue (relu+LN2) -> V1 --------
    if (w0) {
        float v[2];
#pragma unroll
        for (int i = 0; i < 2; ++i) {
            const int o = l + 64 * i;
            double ca = 0.0;
#pragma unroll
            for (int cc = 0; cc < 8; ++cc) ca += dpart[o + cc * HN];
            v[i] = fmaxf((float)ca + P[P_R1B + o], 0.0f);
        }
        double m, rs; w0_stats<2>(v, m, rs);
        V1[l]      = (float)(((double)v[0] - m) * rs) * P[P_N2G + l] + P[P_N2B + l];
        V1[l + 64] = (float)(((double)v[1] - m) * rs) * P[P_N2G + l + 64] + P[P_N2B + l + 64];
    }
    BARRIER();                                     // B6

    // -------- S7: res0 lin2 dot --------
    dpart[t] = dotg<HN, HN>(r2w, V1, t);
    t_e1.issue(e1w, t);
    t_r2b.sink();
    BARRIER();                                     // B7

    // -------- S8: res0 residual; fused LN1b -> V1 --------
    if (w0) {
        float r2o[2];
#pragma unroll
        for (int i = 0; i < 2; ++i) {
            const int o = l + 64 * i;
            double ca = 0.0;
#pragma unroll
            for (int cc = 0; cc < 8; ++cc) ca += dpart[o + cc * HN];
            r2o[i] = (float)ca + P[P_R2B + o];
        }
        h0 = h0 + 0.1f * (r2o[0] + h0);
        h1 = h1 + 0.1f * (r2o[1] + h1);
        float hv[2] = {h0, h1};
        double m1, rs1; w0_stats<2>(hv, m1, rs1);  // LN1b fused
        V1[l]      = (float)(((double)h0 - m1) * rs1) * P[P_N1G + HN + l] + P[P_N1B + HN + l];
        V1[l + 64] = (float)(((double)h1 - m1) * rs1) * P[P_N1G + HN + l + 64] + P[P_N1B + HN + l + 64];
    }
    BARRIER();                                     // B8

    // -------- S9: res1 lin1 dot --------
    dpart[t] = dotg<HN, HN>(r1w + HN * HN, V1, t);
    t_e1.sink();
    BARRIER();                                     // B9

    // -------- S10: res1 lin1 epilogue (relu+LN2) -> V1 --------
    if (w0) {
        float v[2];
#pragma unroll
        for (int i = 0; i < 2; ++i) {
            const int o = l + 64 * i;
            double ca = 0.0;
#pragma unroll
            for (int cc = 0; cc < 8; ++cc) ca += dpart[o + cc * HN];
            v[i] = fmaxf((float)ca + P[P_R1B + HN + o], 0.0f);
        }
        double m, rs; w0_stats<2>(v, m, rs);
        V1[l]      = (float)(((double)v[0] - m) * rs) * P[P_N2G + HN + l] + P[P_N2B + HN + l];
        V1[l + 64] = (float)(((double)v[1] - m) * rs) * P[P_N2G + HN + l + 64] + P[P_N2B + HN + l + 64];
    }
    BARRIER();                                     // B10

    // -------- S11: res1 lin2 dot --------
    dpart[t] = dotg<HN, HN>(r2w + HN * HN, V1, t);
    BARRIER();                                     // B11

    // -------- S12: res1 residual -> V0 (raw h; 1/256 applied in e1 dot) ------
    if (w0) {
        float r2o[2];
#pragma unroll
        for (int i = 0; i < 2; ++i) {
            const int o = l + 64 * i;
            double ca = 0.0;
#pragma unroll
            for (int cc = 0; cc < 8; ++cc) ca += dpart[o + cc * HN];
            r2o[i] = (float)ca + P[P_R2B + HN + o];
        }
        h0 = h0 + 0.1f * (r2o[0] + h0);
        h1 = h1 + 0.1f * (r2o[1] + h1);
        V0[l]      = h0;
        V0[l + 64] = h1;
    }
    BARRIER();                                     // B12

    // -------- S13: e1 dot on [hf, hf] (hf = h/256, exact pow2 after dot) -----
    dpart[t] = dotg_mask127<H2N, HN>(e1w, V0, t) * 0.00390625;
    BARRIER();                                     // B13

    // -------- S14: e1 epilogue + e2 head --------
    if (w0) {
        float v[2];
#pragma unroll
        for (int i = 0; i < 2; ++i) {
            const int o = l + 64 * i;
            double ca = 0.0;
#pragma unroll
            for (int cc = 0; cc < 8; ++cc) ca += dpart[o + cc * HN];
            v[i] = fmaxf((float)ca + P[P_E1B + o], 0.0f);
        }
        double m, rs; w0_stats<2>(v, m, rs);
        const float eo0 = (float)(((double)v[0] - m) * rs) * P[P_EG + l] + P[P_EB + l];
        const float eo1 = (float)(((double)v[1] - m) * rs) * P[P_EG + l + 64] + P[P_EB + l + 64];
        double p0 = (double)eo0 * (double)P[P_E2W + 2 * l];
        p0 = fma((double)eo1, (double)P[P_E2W + 2 * (l + 64)], p0);
        double p1 = (double)eo0 * (double)P[P_E2W + 2 * l + 1];
        p1 = fma((double)eo1, (double)P[P_E2W + 2 * (l + 64) + 1], p1);
#pragma unroll
        for (int s = 1; s < 64; s <<= 1) {
            p0 += __shfl_xor(p0, s, 64);
            p1 += __shfl_xor(p1, s, 64);
        }
        if (l == 0) {
            out_logits[b * 2]     = (float)p0 + P[P_E2B];
            out_logits[b * 2 + 1] = (float)p1 + P[P_E2B + 1];
        }
    }
}

// ---------------- per-pair gumbel decisions + scatter ----------------
__device__ __forceinline__ int rowbase(int i) { return (i * (2 * NNODE - 1 - i)) >> 1; }

__global__ __launch_bounds__(256) void edges_kernel(const float* __restrict__ lg,
                                                    const float* __restrict__ tptr,
                                                    float* __restrict__ out)
{
    int q = blockIdx.x * blockDim.x + threadIdx.x;
    if (q >= NQ) return;
    // diagonal zeros (poison-safe: every output element is written each call)
    if (q < BN * NNODE) {
        int bb = q >> 8, ii = q & 255;
        out[(bb << 16) | (ii << 8) | ii] = 0.0f;
    }
    float temp = fminf(fmaxf(tptr[0], 0.1f), 2.0f);

    int b = q / NPAIR;
    int p = q - b * NPAIR;
    double disc = 261121.0 - 8.0 * (double)p;  // 511^2 - 8p
    int i = (int)((511.0 - sqrt(disc)) * 0.5);
    if (i < 0) i = 0;
    if (i > NNODE - 2) i = NNODE - 2;
    while (rowbase(i + 1) <= p) ++i;
    while (rowbase(i) > p) --i;
    int j = p - rowbase(i) + i + 1;

    uint32_t w0 = bits_partitionable((uint32_t)(2 * q));
    uint32_t w1 = bits_partitionable((uint32_t)(2 * q + 1));

    float u0 = bits_to_u(w0), u1 = bits_to_u(w1);
    float g0 = (float)(-log(-log((double)u0)));
    float g1 = (float)(-log(-log((double)u1)));
    float l0 = lg[2 * b], l1 = lg[2 * b + 1];
    float A0 = (l0 + g0) / temp, A1 = (l1 + g1) / temp;
    float mx = fmaxf(A0, A1);
    float e0 = expf(A0 - mx), e1 = expf(A1 - mx);
    float ssum = e0 + e1;
    float y0 = e0 / ssum, y1 = e1 / ssum;
    float xe = (y0 >= y1) ? 1.0f : 0.0f;
    out[(b << 16) | (i << 8) | j] = xe;
    out[(b << 16) | (j << 8) | i] = xe;
}

extern "C" void kernel_launch(void* const* d_in, const int* in_sizes, int n_in,
                              void* d_out, int out_size, void* d_ws, size_t ws_size,
                              hipStream_t stream)
{
    const float* x    = (const float*)d_in[0];
    const float* st   = (const float*)d_in[1];
    const float* ipw  = (const float*)d_in[2];
    const float* ipb  = (const float*)d_in[3];
    const float* ipg  = (const float*)d_in[4];
    const float* ipbb = (const float*)d_in[5];
    const float* drw  = (const float*)d_in[6];
    const float* drb  = (const float*)d_in[7];
    const float* drg  = (const float*)d_in[8];
    const float* drbb = (const float*)d_in[9];
    const float* r1w  = (const float*)d_in[10];
    const float* r1b  = (const float*)d_in[11];
    const float* r2w  = (const float*)d_in[12];
    const float* r2b  = (const float*)d_in[13];
    const float* n1g  = (const float*)d_in[14];
    const float* n1b  = (const float*)d_in[15];
    const float* n2g  = (const float*)d_in[16];
    const float* n2b  = (const float*)d_in[17];
    // d_in[18] attn_w, d_in[19] attn_b: unused (softmax over identical nodes is uniform)
    const float* e1w  = (const float*)d_in[20];
    const float* e1b  = (const float*)d_in[21];
    const float* eg   = (const float*)d_in[22];
    const float* eb   = (const float*)d_in[23];
    const float* e2w  = (const float*)d_in[24];
    const float* e2b  = (const float*)d_in[25];
    const float* temp = (const float*)d_in[26];
    float* out = (float*)d_out;
    float* lg  = (float*)d_ws;   // 32 floats: per-batch logits

    hipLaunchKernelGGL(logits_kernel, dim3(BN), dim3(NT), 0, stream,
        x, st, ipw, ipb, ipg, ipbb, drw, drb, drg, drbb,
        r1w, r1b, r2w, r2b, n1g, n1b, n2g, n2b,
        e1w, e1b, eg, eb, e2w, e2b, lg);
    hipLaunchKernelGGL(edges_kernel, dim3((NQ + 255) / 256), dim3(256), 0, stream,
        lg, temp, out);
}

// Round 11
// 33.373 us; speedup vs baseline: 1.0527x; 1.0527x over previous
//
#include <hip/hip_runtime.h>
#include <stdint.h>
#include <math.h>

#define BN 16
#define LATN 64
#define STATSN 7
#define ZN 71
#define HN 128
#define H2N 256
#define NNODE 256
#define NPAIR 32640            // N*(N-1)/2
#define NQ 522240              // BN*NPAIR
#define NT 1024                // logits block size (16 waves)

// Raw barrier: drain LDS only (lgkmcnt); leave global prefetches in flight.
#define BARRIER() asm volatile("s_waitcnt lgkmcnt(0)\n\ts_barrier" ::: "memory")

// ---------------- Threefry-2x32, 20 rounds, key = (0, 42) ----------------
__device__ __forceinline__ void tf2x32(uint32_t x0, uint32_t x1,
                                       uint32_t& o0, uint32_t& o1) {
    const uint32_t ks0 = 0u, ks1 = 42u, ks2 = 0x1BD11BF0u;  // 0^42^0x1BD11BDA
    x0 += ks0; x1 += ks1;
#define TFRND(r) { x0 += x1; x1 = (x1 << (r)) | (x1 >> (32 - (r))); x1 ^= x0; }
    TFRND(13) TFRND(15) TFRND(26) TFRND(6)
    x0 += ks1; x1 += ks2 + 1u;
    TFRND(17) TFRND(29) TFRND(16) TFRND(24)
    x0 += ks2; x1 += ks0 + 2u;
    TFRND(13) TFRND(15) TFRND(26) TFRND(6)
    x0 += ks0; x1 += ks1 + 3u;
    TFRND(17) TFRND(29) TFRND(16) TFRND(24)
    x0 += ks1; x1 += ks2 + 4u;
    TFRND(13) TFRND(15) TFRND(26) TFRND(6)
    x0 += ks2; x1 += ks0 + 5u;
#undef TFRND
    o0 = x0; o1 = x1;
}

__device__ __forceinline__ uint32_t bits_partitionable(uint32_t m) {
    uint32_t o0, o1;
    tf2x32(0u, m, o0, o1);
    return o0 ^ o1;
}

__device__ __forceinline__ float bits_to_u(uint32_t w) {
    float f = __uint_as_float((w >> 9) | 0x3f800000u) - 1.0f;
    const float mn = 1e-9f;
    return fmaxf(mn, f * (1.0f - mn) + mn);
}

// ---------------- L2 warming kernel ----------------
// 64 blocks: XCD = blockIdx&7 (round-robin dispatch), slice = blockIdx>>3.
// Each XCD's 8 resident blocks together stream ALL weight bytes -> that
// XCD's L2 holds the full set before logits_kernel runs. Reads only.
__device__ __forceinline__ float warm_arr(const float4* __restrict__ a,
                                          int n4, int base) {
    float acc = 0.0f;
    for (int i = base; i < n4; i += 8192) {
        const float4 v = a[i];
        acc += v.x + v.y + v.z + v.w;
    }
    return acc;
}

__global__ __launch_bounds__(1024) void warm_kernel(
    const float4* __restrict__ ipw, const float4* __restrict__ drw,
    const float4* __restrict__ r1w, const float4* __restrict__ r2w,
    const float4* __restrict__ e1w)
{
    const int base = ((int)blockIdx.x >> 3) * 1024 + (int)threadIdx.x;
    float acc = 0.0f;
    acc += warm_arr(ipw, 4544, base);   // 71*256/4
    acc += warm_arr(drw, 8192, base);   // 256*128/4
    acc += warm_arr(r1w, 8192, base);   // 2*128*128/4
    acc += warm_arr(r2w, 8192, base);   // 2*128*128/4
    acc += warm_arr(e1w, 8192, base);   // 256*128/4
    asm volatile("" :: "v"(acc));       // keep loads live; no memory writes
}

// ---------------- register-resident weight slice (1024 threads) ----------------
template<int K, int O>
struct WS {
    static constexpr int C    = NT / O;      // 4 for O=256, 8 for O=128
    static constexpr int KC   = (K + C - 1) / C;
    static constexpr int LOGO = (O == 256) ? 8 : 7;
    float w[KC];
    __device__ __forceinline__ void load(const float* __restrict__ W, int t) {
        const int out = t & (O - 1);
        const int k0 = (t >> LOGO) * KC;
#pragma unroll
        for (int i = 0; i < KC; ++i) {
            const int k = k0 + i;
            w[i] = ((K % C == 0) || k < K) ? W[k * O + out] : 0.0f;
        }
    }
    // r3/r6-verified fma pairing (a0/a1 alternate, a0+a1 combine)
    __device__ __forceinline__ double dot(const float* __restrict__ vin, int t) const {
        const int k0 = (t >> LOGO) * KC;
        double a0 = 0.0, a1 = 0.0;
#pragma unroll
        for (int i = 0; i < KC; i += 2) {
            a0 = fma((double)vin[k0 + i], (double)w[i], a0);
            if (i + 1 < KC) a1 = fma((double)vin[k0 + i + 1], (double)w[i + 1], a1);
        }
        return a0 + a1;
    }
    __device__ __forceinline__ double dot_mask127(const float* __restrict__ vin, int t) const {
        const int k0 = (t >> LOGO) * KC;
        double a0 = 0.0, a1 = 0.0;
#pragma unroll
        for (int i = 0; i < KC; i += 2) {
            a0 = fma((double)vin[(k0 + i) & 127], (double)w[i], a0);
            if (i + 1 < KC) a1 = fma((double)vin[(k0 + i + 1) & 127], (double)w[i + 1], a1);
        }
        return a0 + a1;
    }
};

// wave0 LN stats: butterfly; rsqrt = f32 seed + 2 f64 Newton steps (r8-verified)
template<int NV>
__device__ __forceinline__ void w0_stats(const float* v, double& m, double& rs) {
    double a = 0.0, q = 0.0;
#pragma unroll
    for (int i = 0; i < NV; ++i) {
        a += (double)v[i];
        q += (double)v[i] * (double)v[i];
    }
#pragma unroll
    for (int s = 1; s < 64; s <<= 1) {
        a += __shfl_xor(a, s, 64);
        q += __shfl_xor(q, s, 64);
    }
    constexpr double O = (double)(NV * 64);
    m = a * (1.0 / O);
    const double d = q * (1.0 / O) - m * m + 1e-5;
    double r = (double)rsqrtf((float)d);
    r = r * (1.5 - 0.5 * d * r * r);
    r = r * (1.5 - 0.5 * d * r * r);
    rs = r;
}

// epilogue-parameter LDS layout (floats)
#define P_IPB   0
#define P_IPG   256
#define P_IPBB  512
#define P_DRB   768
#define P_DRG   896
#define P_DRBB  1024
#define P_R1B   1152   /* 256: both layers */
#define P_N1G   1408
#define P_N1B   1664
#define P_N2G   1920
#define P_N2B   2176
#define P_R2B   2432
#define P_E1B   2688
#define P_EG    2816
#define P_EB    2944
#define P_E2W   3072   /* 256 */
#define P_E2B   3328   /* 2 */
#define P_SIZE  3332

__global__ __launch_bounds__(NT, 1) void logits_kernel(
    const float* __restrict__ x, const float* __restrict__ st,
    const float* __restrict__ ipw, const float* __restrict__ ipb,
    const float* __restrict__ ipg, const float* __restrict__ ipbb,
    const float* __restrict__ drw, const float* __restrict__ drb,
    const float* __restrict__ drg, const float* __restrict__ drbb,
    const float* __restrict__ r1w, const float* __restrict__ r1b,
    const float* __restrict__ r2w, const float* __restrict__ r2b,
    const float* __restrict__ n1g, const float* __restrict__ n1b,
    const float* __restrict__ n2g, const float* __restrict__ n2b,
    const float* __restrict__ e1w, const float* __restrict__ e1b,
    const float* __restrict__ eg,  const float* __restrict__ eb,
    const float* __restrict__ e2w, const float* __restrict__ e2b,
    float* __restrict__ out_logits)
{
    __shared__ __align__(16) float V0[H2N];
    __shared__ __align__(16) float V1[H2N];
    __shared__ double dpart[NT];
    __shared__ float P[P_SIZE];
    const int t = threadIdx.x;
    const int b = blockIdx.x;
    const int l = t & 63;
    const bool w0 = (t < 64);

    // weight slices, loads issued ~2 phases ahead of use
    WS<ZN, H2N> w_ip;
    WS<H2N, HN> w_dr;
    WS<HN, HN>  w_r1a, w_r2a, w_r1b, w_r2b;
    WS<H2N, HN> w_e1;

    // -------- prologue: params -> LDS, z -> V0, first two weight slices ------
    w_ip.load(ipw, t);
    w_dr.load(drw, t);
    if (t < 256) {
        P[P_IPB + t] = ipb[t];  P[P_IPG + t] = ipg[t];  P[P_IPBB + t] = ipbb[t];
        P[P_R1B + t] = r1b[t];  P[P_N1G + t] = n1g[t];  P[P_N1B + t] = n1b[t];
        P[P_N2G + t] = n2g[t];  P[P_N2B + t] = n2b[t];  P[P_R2B + t] = r2b[t];
        P[P_E2W + t] = e2w[t];
    } else if (t < 384) {
        const int i = t - 256;
        P[P_DRB + i] = drb[i];  P[P_DRG + i] = drg[i];  P[P_DRBB + i] = drbb[i];
        P[P_E1B + i] = e1b[i];  P[P_EG + i] = eg[i];    P[P_EB + i] = eb[i];
    } else if (t < 386) {
        P[P_E2B + (t - 384)] = e2b[t - 384];
    }
    if (t < LATN)      V0[t] = x[b * LATN + t];
    else if (t < ZN)   V0[t] = st[b * STATSN + (t - LATN)];
    else if (t < H2N)  V0[t] = 0.0f;     // zero-pad so padded w entries hit 0
    BARRIER();                                     // B0

    float h0 = 0.0f, h1 = 0.0f;   // running h, wave0 regs only

    // -------- ip: [71]->relu->LN(256) -> V1 --------
    dpart[t] = w_ip.dot(V0, t);
    BARRIER();                                     // B1
    w_r1a.load(r1w, t);                            // prefetch (used B4-B5)
    if (w0) {
        float v[4];
#pragma unroll
        for (int i = 0; i < 4; ++i) {
            const int o = l + 64 * i;
            double ca = 0.0;
#pragma unroll
            for (int cc = 0; cc < 4; ++cc) ca += dpart[o + cc * H2N];
            v[i] = fmaxf((float)ca + P[P_IPB + o], 0.0f);
        }
        double m, rs; w0_stats<4>(v, m, rs);
#pragma unroll
        for (int i = 0; i < 4; ++i) {
            const int o = l + 64 * i;
            V1[o] = (float)(((double)v[i] - m) * rs) * P[P_IPG + o] + P[P_IPBB + o];
        }
    }
    BARRIER();                                     // B2

    // -------- dr: [256]->[128], relu, LN -> h (regs); fused LN1a -> V1 -------
    dpart[t] = w_dr.dot(V1, t);
    BARRIER();                                     // B3
    w_r2a.load(r2w, t);                            // prefetch (used B6-B7)
    if (w0) {
        float v[2];
#pragma unroll
        for (int i = 0; i < 2; ++i) {
            const int o = l + 64 * i;
            double ca = 0.0;
#pragma unroll
            for (int cc = 0; cc < 8; ++cc) ca += dpart[o + cc * HN];
            v[i] = fmaxf((float)ca + P[P_DRB + o], 0.0f);
        }
        double m, rs; w0_stats<2>(v, m, rs);
        h0 = (float)(((double)v[0] - m) * rs) * P[P_DRG + l] + P[P_DRBB + l];
        h1 = (float)(((double)v[1] - m) * rs) * P[P_DRG + l + 64] + P[P_DRBB + l + 64];
        float hv[2] = {h0, h1};
        double m1, rs1; w0_stats<2>(hv, m1, rs1);  // LN1a fused
        V1[l]      = (float)(((double)h0 - m1) * rs1) * P[P_N1G + l] + P[P_N1B + l];
        V1[l + 64] = (float)(((double)h1 - m1) * rs1) * P[P_N1G + l + 64] + P[P_N1B + l + 64];
    }
    BARRIER();                                     // B4

    // -------- res0 lin1 + relu + LN2 -> V1 --------
    dpart[t] = w_r1a.dot(V1, t);
    BARRIER();                                     // B5
    w_r1b.load(r1w + HN * HN, t);                  // prefetch (used B8-B9)
    if (w0) {
        float v[2];
#pragma unroll
        for (int i = 0; i < 2; ++i) {
            const int o = l + 64 * i;
            double ca = 0.0;
#pragma unroll
            for (int cc = 0; cc < 8; ++cc) ca += dpart[o + cc * HN];
            v[i] = fmaxf((float)ca + P[P_R1B + o], 0.0f);
        }
        double m, rs; w0_stats<2>(v, m, rs);
        V1[l]      = (float)(((double)v[0] - m) * rs) * P[P_N2G + l] + P[P_N2B + l];
        V1[l + 64] = (float)(((double)v[1] - m) * rs) * P[P_N2G + l + 64] + P[P_N2B + l + 64];
    }
    BARRIER();                                     // B6

    // -------- res0 lin2 + residual; fused LN1b -> V1 --------
    dpart[t] = w_r2a.dot(V1, t);
    BARRIER();                                     // B7
    w_r2b.load(r2w + HN * HN, t);                  // prefetch (used B10-B11)
    if (w0) {
        float r2o[2];
#pragma unroll
        for (int i = 0; i < 2; ++i) {
            const int o = l + 64 * i;
            double ca = 0.0;
#pragma unroll
            for (int cc = 0; cc < 8; ++cc) ca += dpart[o + cc * HN];
            r2o[i] = (float)ca + P[P_R2B + o];
        }
        h0 = h0 + 0.1f * (r2o[0] + h0);
        h1 = h1 + 0.1f * (r2o[1] + h1);
        float hv[2] = {h0, h1};
        double m1, rs1; w0_stats<2>(hv, m1, rs1);  // LN1b fused
        V1[l]      = (float)(((double)h0 - m1) * rs1) * P[P_N1G + HN + l] + P[P_N1B + HN + l];
        V1[l + 64] = (float)(((double)h1 - m1) * rs1) * P[P_N1G + HN + l + 64] + P[P_N1B + HN + l + 64];
    }
    BARRIER();                                     // B8

    // -------- res1 lin1 + relu + LN2 -> V1 --------
    dpart[t] = w_r1b.dot(V1, t);
    BARRIER();                                     // B9
    w_e1.load(e1w, t);                             // prefetch (used B12-B13)
    if (w0) {
        float v[2];
#pragma unroll
        for (int i = 0; i < 2; ++i) {
            const int o = l + 64 * i;
            double ca = 0.0;
#pragma unroll
            for (int cc = 0; cc < 8; ++cc) ca += dpart[o + cc * HN];
            v[i] = fmaxf((float)ca + P[P_R1B + HN + o], 0.0f);
        }
        double m, rs; w0_stats<2>(v, m, rs);
        V1[l]      = (float)(((double)v[0] - m) * rs) * P[P_N2G + HN + l] + P[P_N2B + HN + l];
        V1[l + 64] = (float)(((double)v[1] - m) * rs) * P[P_N2G + HN + l + 64] + P[P_N2B + HN + l + 64];
    }
    BARRIER();                                     // B10

    // -------- res1 lin2 + residual -> V0 (raw h; 1/256 applied in e1 dot) ----
    dpart[t] = w_r2b.dot(V1, t);
    BARRIER();                                     // B11
    if (w0) {
        float r2o[2];
#pragma unroll
        for (int i = 0; i < 2; ++i) {
            const int o = l + 64 * i;
            double ca = 0.0;
#pragma unroll
            for (int cc = 0; cc < 8; ++cc) ca += dpart[o + cc * HN];
            r2o[i] = (float)ca + P[P_R2B + HN + o];
        }
        h0 = h0 + 0.1f * (r2o[0] + h0);
        h1 = h1 + 0.1f * (r2o[1] + h1);
        V0[l]      = h0;
        V0[l + 64] = h1;
    }
    BARRIER();                                     // B12

    // -------- e1 on [hf, hf] (hf = h/256, exact pow2 scale after dot) --------
    dpart[t] = w_e1.dot_mask127(V0, t) * 0.00390625;
    BARRIER();                                     // B13
    if (w0) {
        float v[2];
#pragma unroll
        for (int i = 0; i < 2; ++i) {
            const int o = l + 64 * i;
            double ca = 0.0;
#pragma unroll
            for (int cc = 0; cc < 8; ++cc) ca += dpart[o + cc * HN];
            v[i] = fmaxf((float)ca + P[P_E1B + o], 0.0f);
        }
        double m, rs; w0_stats<2>(v, m, rs);
        const float eo0 = (float)(((double)v[0] - m) * rs) * P[P_EG + l] + P[P_EB + l];
        const float eo1 = (float)(((double)v[1] - m) * rs) * P[P_EG + l + 64] + P[P_EB + l + 64];
        // e2 head: fully in-wave
        double p0 = (double)eo0 * (double)P[P_E2W + 2 * l];
        p0 = fma((double)eo1, (double)P[P_E2W + 2 * (l + 64)], p0);
        double p1 = (double)eo0 * (double)P[P_E2W + 2 * l + 1];
        p1 = fma((double)eo1, (double)P[P_E2W + 2 * (l + 64) + 1], p1);
#pragma unroll
        for (int s = 1; s < 64; s <<= 1) {
            p0 += __shfl_xor(p0, s, 64);
            p1 += __shfl_xor(p1, s, 64);
        }
        if (l == 0) {
            out_logits[b * 2]     = (float)p0 + P[P_E2B];
            out_logits[b * 2 + 1] = (float)p1 + P[P_E2B + 1];
        }
    }
}

// ---------------- per-pair gumbel decisions + scatter ----------------
__device__ __forceinline__ int rowbase(int i) { return (i * (2 * NNODE - 1 - i)) >> 1; }

__global__ __launch_bounds__(256) void edges_kernel(const float* __restrict__ lg,
                                                    const float* __restrict__ tptr,
                                                    float* __restrict__ out)
{
    int q = blockIdx.x * blockDim.x + threadIdx.x;
    if (q >= NQ) return;
    // diagonal zeros (poison-safe: every output element is written each call)
    if (q < BN * NNODE) {
        int bb = q >> 8, ii = q & 255;
        out[(bb << 16) | (ii << 8) | ii] = 0.0f;
    }
    float temp = fminf(fmaxf(tptr[0], 0.1f), 2.0f);

    int b = q / NPAIR;
    int p = q - b * NPAIR;
    double disc = 261121.0 - 8.0 * (double)p;  // 511^2 - 8p
    int i = (int)((511.0 - sqrt(disc)) * 0.5);
    if (i < 0) i = 0;
    if (i > NNODE - 2) i = NNODE - 2;
    while (rowbase(i + 1) <= p) ++i;
    while (rowbase(i) > p) --i;
    int j = p - rowbase(i) + i + 1;

    uint32_t w0 = bits_partitionable((uint32_t)(2 * q));
    uint32_t w1 = bits_partitionable((uint32_t)(2 * q + 1));

    float u0 = bits_to_u(w0), u1 = bits_to_u(w1);
    float g0 = (float)(-log(-log((double)u0)));
    float g1 = (float)(-log(-log((double)u1)));
    float l0 = lg[2 * b], l1 = lg[2 * b + 1];
    float A0 = (l0 + g0) / temp, A1 = (l1 + g1) / temp;
    float mx = fmaxf(A0, A1);
    float e0 = expf(A0 - mx), e1 = expf(A1 - mx);
    float ssum = e0 + e1;
    float y0 = e0 / ssum, y1 = e1 / ssum;
    float xe = (y0 >= y1) ? 1.0f : 0.0f;
    out[(b << 16) | (i << 8) | j] = xe;
    out[(b << 16) | (j << 8) | i] = xe;
}

extern "C" void kernel_launch(void* const* d_in, const int* in_sizes, int n_in,
                              void* d_out, int out_size, void* d_ws, size_t ws_size,
                              hipStream_t stream)
{
    const float* x    = (const float*)d_in[0];
    const float* st   = (const float*)d_in[1];
    const float* ipw  = (const float*)d_in[2];
    const float* ipb  = (const float*)d_in[3];
    const float* ipg  = (const float*)d_in[4];
    const float* ipbb = (const float*)d_in[5];
    const float* drw  = (const float*)d_in[6];
    const float* drb  = (const float*)d_in[7];
    const float* drg  = (const float*)d_in[8];
    const float* drbb = (const float*)d_in[9];
    const float* r1w  = (const float*)d_in[10];
    const float* r1b  = (const float*)d_in[11];
    const float* r2w  = (const float*)d_in[12];
    const float* r2b  = (const float*)d_in[13];
    const float* n1g  = (const float*)d_in[14];
    const float* n1b  = (const float*)d_in[15];
    const float* n2g  = (const float*)d_in[16];
    const float* n2b  = (const float*)d_in[17];
    // d_in[18] attn_w, d_in[19] attn_b: unused (softmax over identical nodes is uniform)
    const float* e1w  = (const float*)d_in[20];
    const float* e1b  = (const float*)d_in[21];
    const float* eg   = (const float*)d_in[22];
    const float* eb   = (const float*)d_in[23];
    const float* e2w  = (const float*)d_in[24];
    const float* e2b  = (const float*)d_in[25];
    const float* temp = (const float*)d_in[26];
    float* out = (float*)d_out;
    float* lg  = (float*)d_ws;   // 32 floats: per-batch logits

    // 1) warm every XCD's L2 with the full weight set (reads only, ~1-2 us)
    hipLaunchKernelGGL(warm_kernel, dim3(64), dim3(1024), 0, stream,
        (const float4*)ipw, (const float4*)drw, (const float4*)r1w,
        (const float4*)r2w, (const float4*)e1w);
    // 2) per-batch logits (r9 kernel, byte-identical math)
    hipLaunchKernelGGL(logits_kernel, dim3(BN), dim3(NT), 0, stream,
        x, st, ipw, ipb, ipg, ipbb, drw, drb, drg, drbb,
        r1w, r1b, r2w, r2b, n1g, n1b, n2g, n2b,
        e1w, e1b, eg, eb, e2w, e2b, lg);
    // 3) per-pair gumbel decisions + scatter
    hipLaunchKernelGGL(edges_kernel, dim3((NQ + 255) / 256), dim3(256), 0, stream,
        lg, temp, out);
}

// Round 12
// 23.949 us; speedup vs baseline: 1.4670x; 1.3935x over previous
//
#include <hip/hip_runtime.h>
#include <stdint.h>
#include <math.h>

#define BN 16
#define LATN 64
#define STATSN 7
#define ZN 71
#define HN 128
#define H2N 256
#define NNODE 256
#define NPAIR 32640            // N*(N-1)/2
#define NQ 522240              // BN*NPAIR
#define NT 1024                // logits block size (16 waves)

// Raw barrier: drain LDS only (lgkmcnt); leave global prefetches in flight.
#define BARRIER() asm volatile("s_waitcnt lgkmcnt(0)\n\ts_barrier" ::: "memory")

// ---------------- Threefry-2x32, 20 rounds, key = (0, 42) ----------------
__device__ __forceinline__ void tf2x32(uint32_t x0, uint32_t x1,
                                       uint32_t& o0, uint32_t& o1) {
    const uint32_t ks0 = 0u, ks1 = 42u, ks2 = 0x1BD11BF0u;  // 0^42^0x1BD11BDA
    x0 += ks0; x1 += ks1;
#define TFRND(r) { x0 += x1; x1 = (x1 << (r)) | (x1 >> (32 - (r))); x1 ^= x0; }
    TFRND(13) TFRND(15) TFRND(26) TFRND(6)
    x0 += ks1; x1 += ks2 + 1u;
    TFRND(17) TFRND(29) TFRND(16) TFRND(24)
    x0 += ks2; x1 += ks0 + 2u;
    TFRND(13) TFRND(15) TFRND(26) TFRND(6)
    x0 += ks0; x1 += ks1 + 3u;
    TFRND(17) TFRND(29) TFRND(16) TFRND(24)
    x0 += ks1; x1 += ks2 + 4u;
    TFRND(13) TFRND(15) TFRND(26) TFRND(6)
    x0 += ks2; x1 += ks0 + 5u;
#undef TFRND
    o0 = x0; o1 = x1;
}

__device__ __forceinline__ uint32_t bits_partitionable(uint32_t m) {
    uint32_t o0, o1;
    tf2x32(0u, m, o0, o1);
    return o0 ^ o1;
}

__device__ __forceinline__ float bits_to_u(uint32_t w) {
    float f = __uint_as_float((w >> 9) | 0x3f800000u) - 1.0f;
    const float mn = 1e-9f;
    return fmaxf(mn, f * (1.0f - mn) + mn);
}

// ---------------- fast bit-exact 64-lane butterfly transport ----------------
// Lane-routing equivalences (value added is bitwise identical to __shfl_xor):
//   xor1 -> quad_perm(1,0,3,2)=0xB1 ; xor2 -> quad_perm(2,3,0,1)=0x4E
//   xor4 -> row_half_mirror (0x141): partner i^7 is in the i^4 quad, which
//           holds the identical quad-sum after levels 1,2
//   xor8 -> row_mirror (0x140): partner i^15 is in the i^8 8-group (identical)
//   xor16 -> ds_swizzle xor-mask 0x401F ; xor32 -> __shfl_xor (cross-half)
template<int CTRL>
__device__ __forceinline__ double dppd(double x) {
    int lo = __double2loint(x), hi = __double2hiint(x);
    lo = __builtin_amdgcn_update_dpp(0, lo, CTRL, 0xF, 0xF, true);
    hi = __builtin_amdgcn_update_dpp(0, hi, CTRL, 0xF, 0xF, true);
    return __hiloint2double(hi, lo);
}
__device__ __forceinline__ double swz16d(double x) {
    int lo = __double2loint(x), hi = __double2hiint(x);
    lo = __builtin_amdgcn_ds_swizzle(lo, 0x401F);
    hi = __builtin_amdgcn_ds_swizzle(hi, 0x401F);
    return __hiloint2double(hi, lo);
}
__device__ __forceinline__ void bfly_pair(double& a, double& q) {
    a += dppd<0xB1>(a);   q += dppd<0xB1>(q);    // xor1
    a += dppd<0x4E>(a);   q += dppd<0x4E>(q);    // xor2
    a += dppd<0x141>(a);  q += dppd<0x141>(q);   // xor4-equiv
    a += dppd<0x140>(a);  q += dppd<0x140>(q);   // xor8-equiv
    a += swz16d(a);       q += swz16d(q);        // xor16
    a += __shfl_xor(a, 32, 64);
    q += __shfl_xor(q, 32, 64);                  // xor32
}

// ---------------- register-resident weight slice (1024 threads) ----------------
template<int K, int O>
struct WS {
    static constexpr int C    = NT / O;      // 4 for O=256, 8 for O=128
    static constexpr int KC   = (K + C - 1) / C;
    static constexpr int LOGO = (O == 256) ? 8 : 7;
    float w[KC];
    __device__ __forceinline__ void load(const float* __restrict__ W, int t) {
        const int out = t & (O - 1);
        const int k0 = (t >> LOGO) * KC;
#pragma unroll
        for (int i = 0; i < KC; ++i) {
            const int k = k0 + i;
            w[i] = ((K % C == 0) || k < K) ? W[k * O + out] : 0.0f;
        }
    }
    // r3/r6-verified fma pairing (a0/a1 alternate, a0+a1 combine)
    __device__ __forceinline__ double dot(const float* __restrict__ vin, int t) const {
        const int k0 = (t >> LOGO) * KC;
        double a0 = 0.0, a1 = 0.0;
#pragma unroll
        for (int i = 0; i < KC; i += 2) {
            a0 = fma((double)vin[k0 + i], (double)w[i], a0);
            if (i + 1 < KC) a1 = fma((double)vin[k0 + i + 1], (double)w[i + 1], a1);
        }
        return a0 + a1;
    }
    __device__ __forceinline__ double dot_mask127(const float* __restrict__ vin, int t) const {
        const int k0 = (t >> LOGO) * KC;
        double a0 = 0.0, a1 = 0.0;
#pragma unroll
        for (int i = 0; i < KC; i += 2) {
            a0 = fma((double)vin[(k0 + i) & 127], (double)w[i], a0);
            if (i + 1 < KC) a1 = fma((double)vin[(k0 + i + 1) & 127], (double)w[i + 1], a1);
        }
        return a0 + a1;
    }
};

// wave0 LN stats: fast butterfly; rsqrt = f32 seed + 2 f64 Newton (r8-verified)
template<int NV>
__device__ __forceinline__ void w0_stats(const float* v, double& m, double& rs) {
    double a = 0.0, q = 0.0;
#pragma unroll
    for (int i = 0; i < NV; ++i) {
        a += (double)v[i];
        q += (double)v[i] * (double)v[i];
    }
    bfly_pair(a, q);
    constexpr double O = (double)(NV * 64);
    m = a * (1.0 / O);
    const double d = q * (1.0 / O) - m * m + 1e-5;
    double r = (double)rsqrtf((float)d);
    r = r * (1.5 - 0.5 * d * r * r);
    r = r * (1.5 - 0.5 * d * r * r);
    rs = r;
}

// epilogue-parameter LDS layout (floats)
#define P_IPB   0
#define P_IPG   256
#define P_IPBB  512
#define P_DRB   768
#define P_DRG   896
#define P_DRBB  1024
#define P_R1B   1152   /* 256: both layers */
#define P_N1G   1408
#define P_N1B   1664
#define P_N2G   1920
#define P_N2B   2176
#define P_R2B   2432
#define P_E1B   2688
#define P_EG    2816
#define P_EB    2944
#define P_E2W   3072   /* 256 */
#define P_E2B   3328   /* 2 */
#define P_SIZE  3332

__global__ __launch_bounds__(NT, 1) void logits_kernel(
    const float* __restrict__ x, const float* __restrict__ st,
    const float* __restrict__ ipw, const float* __restrict__ ipb,
    const float* __restrict__ ipg, const float* __restrict__ ipbb,
    const float* __restrict__ drw, const float* __restrict__ drb,
    const float* __restrict__ drg, const float* __restrict__ drbb,
    const float* __restrict__ r1w, const float* __restrict__ r1b,
    const float* __restrict__ r2w, const float* __restrict__ r2b,
    const float* __restrict__ n1g, const float* __restrict__ n1b,
    const float* __restrict__ n2g, const float* __restrict__ n2b,
    const float* __restrict__ e1w, const float* __restrict__ e1b,
    const float* __restrict__ eg,  const float* __restrict__ eb,
    const float* __restrict__ e2w, const float* __restrict__ e2b,
    float* __restrict__ out_logits)
{
    __shared__ __align__(16) float V0[H2N];
    __shared__ __align__(16) float V1[H2N];
    __shared__ double dpart[NT];
    __shared__ float P[P_SIZE];
    const int t = threadIdx.x;
    const int b = blockIdx.x;
    const int l = t & 63;
    const bool w0 = (t < 64);

    // weight slices, loads issued ~2 phases ahead of use
    WS<ZN, H2N> w_ip;
    WS<H2N, HN> w_dr;
    WS<HN, HN>  w_r1a, w_r2a, w_r1b, w_r2b;
    WS<H2N, HN> w_e1;

    // -------- prologue: params -> LDS, z -> V0, first two weight slices ------
    w_ip.load(ipw, t);
    w_dr.load(drw, t);
    if (t < 256) {
        P[P_IPB + t] = ipb[t];  P[P_IPG + t] = ipg[t];  P[P_IPBB + t] = ipbb[t];
        P[P_R1B + t] = r1b[t];  P[P_N1G + t] = n1g[t];  P[P_N1B + t] = n1b[t];
        P[P_N2G + t] = n2g[t];  P[P_N2B + t] = n2b[t];  P[P_R2B + t] = r2b[t];
        P[P_E2W + t] = e2w[t];
    } else if (t < 384) {
        const int i = t - 256;
        P[P_DRB + i] = drb[i];  P[P_DRG + i] = drg[i];  P[P_DRBB + i] = drbb[i];
        P[P_E1B + i] = e1b[i];  P[P_EG + i] = eg[i];    P[P_EB + i] = eb[i];
    } else if (t < 386) {
        P[P_E2B + (t - 384)] = e2b[t - 384];
    }
    if (t < LATN)      V0[t] = x[b * LATN + t];
    else if (t < ZN)   V0[t] = st[b * STATSN + (t - LATN)];
    else if (t < H2N)  V0[t] = 0.0f;     // zero-pad so padded w entries hit 0
    BARRIER();                                     // B0

    float h0 = 0.0f, h1 = 0.0f;   // running h, wave0 regs only

    // -------- ip: [71]->relu->LN(256) -> V1 --------
    dpart[t] = w_ip.dot(V0, t);
    BARRIER();                                     // B1
    w_r1a.load(r1w, t);                            // prefetch (used B4-B5)
    if (w0) {
        float v[4];
#pragma unroll
        for (int i = 0; i < 4; ++i) {
            const int o = l + 64 * i;
            double ca = 0.0;
#pragma unroll
            for (int cc = 0; cc < 4; ++cc) ca += dpart[o + cc * H2N];
            v[i] = fmaxf((float)ca + P[P_IPB + o], 0.0f);
        }
        double m, rs; w0_stats<4>(v, m, rs);
#pragma unroll
        for (int i = 0; i < 4; ++i) {
            const int o = l + 64 * i;
            V1[o] = (float)(((double)v[i] - m) * rs) * P[P_IPG + o] + P[P_IPBB + o];
        }
    }
    BARRIER();                                     // B2

    // -------- dr: [256]->[128], relu, LN -> h (regs); fused LN1a -> V1 -------
    dpart[t] = w_dr.dot(V1, t);
    BARRIER();                                     // B3
    w_r2a.load(r2w, t);                            // prefetch (used B6-B7)
    if (w0) {
        float v[2];
#pragma unroll
        for (int i = 0; i < 2; ++i) {
            const int o = l + 64 * i;
            double ca = 0.0;
#pragma unroll
            for (int cc = 0; cc < 8; ++cc) ca += dpart[o + cc * HN];
            v[i] = fmaxf((float)ca + P[P_DRB + o], 0.0f);
        }
        double m, rs; w0_stats<2>(v, m, rs);
        h0 = (float)(((double)v[0] - m) * rs) * P[P_DRG + l] + P[P_DRBB + l];
        h1 = (float)(((double)v[1] - m) * rs) * P[P_DRG + l + 64] + P[P_DRBB + l + 64];
        float hv[2] = {h0, h1};
        double m1, rs1; w0_stats<2>(hv, m1, rs1);  // LN1a fused
        V1[l]      = (float)(((double)h0 - m1) * rs1) * P[P_N1G + l] + P[P_N1B + l];
        V1[l + 64] = (float)(((double)h1 - m1) * rs1) * P[P_N1G + l + 64] + P[P_N1B + l + 64];
    }
    BARRIER();                                     // B4

    // -------- res0 lin1 + relu + LN2 -> V1 --------
    dpart[t] = w_r1a.dot(V1, t);
    BARRIER();                                     // B5
    w_r1b.load(r1w + HN * HN, t);                  // prefetch (used B8-B9)
    if (w0) {
        float v[2];
#pragma unroll
        for (int i = 0; i < 2; ++i) {
            const int o = l + 64 * i;
            double ca = 0.0;
#pragma unroll
            for (int cc = 0; cc < 8; ++cc) ca += dpart[o + cc * HN];
            v[i] = fmaxf((float)ca + P[P_R1B + o], 0.0f);
        }
        double m, rs; w0_stats<2>(v, m, rs);
        V1[l]      = (float)(((double)v[0] - m) * rs) * P[P_N2G + l] + P[P_N2B + l];
        V1[l + 64] = (float)(((double)v[1] - m) * rs) * P[P_N2G + l + 64] + P[P_N2B + l + 64];
    }
    BARRIER();                                     // B6

    // -------- res0 lin2 + residual; fused LN1b -> V1 --------
    dpart[t] = w_r2a.dot(V1, t);
    BARRIER();                                     // B7
    w_r2b.load(r2w + HN * HN, t);                  // prefetch (used B10-B11)
    if (w0) {
        float r2o[2];
#pragma unroll
        for (int i = 0; i < 2; ++i) {
            const int o = l + 64 * i;
            double ca = 0.0;
#pragma unroll
            for (int cc = 0; cc < 8; ++cc) ca += dpart[o + cc * HN];
            r2o[i] = (float)ca + P[P_R2B + o];
        }
        h0 = h0 + 0.1f * (r2o[0] + h0);
        h1 = h1 + 0.1f * (r2o[1] + h1);
        float hv[2] = {h0, h1};
        double m1, rs1; w0_stats<2>(hv, m1, rs1);  // LN1b fused
        V1[l]      = (float)(((double)h0 - m1) * rs1) * P[P_N1G + HN + l] + P[P_N1B + HN + l];
        V1[l + 64] = (float)(((double)h1 - m1) * rs1) * P[P_N1G + HN + l + 64] + P[P_N1B + HN + l + 64];
    }
    BARRIER();                                     // B8

    // -------- res1 lin1 + relu + LN2 -> V1 --------
    dpart[t] = w_r1b.dot(V1, t);
    BARRIER();                                     // B9
    w_e1.load(e1w, t);                             // prefetch (used B12-B13)
    if (w0) {
        float v[2];
#pragma unroll
        for (int i = 0; i < 2; ++i) {
            const int o = l + 64 * i;
            double ca = 0.0;
#pragma unroll
            for (int cc = 0; cc < 8; ++cc) ca += dpart[o + cc * HN];
            v[i] = fmaxf((float)ca + P[P_R1B + HN + o], 0.0f);
        }
        double m, rs; w0_stats<2>(v, m, rs);
        V1[l]      = (float)(((double)v[0] - m) * rs) * P[P_N2G + HN + l] + P[P_N2B + HN + l];
        V1[l + 64] = (float)(((double)v[1] - m) * rs) * P[P_N2G + HN + l + 64] + P[P_N2B + HN + l + 64];
    }
    BARRIER();                                     // B10

    // -------- res1 lin2 + residual -> V0 (raw h; 1/256 applied in e1 dot) ----
    dpart[t] = w_r2b.dot(V1, t);
    BARRIER();                                     // B11
    if (w0) {
        float r2o[2];
#pragma unroll
        for (int i = 0; i < 2; ++i) {
            const int o = l + 64 * i;
            double ca = 0.0;
#pragma unroll
            for (int cc = 0; cc < 8; ++cc) ca += dpart[o + cc * HN];
            r2o[i] = (float)ca + P[P_R2B + HN + o];
        }
        h0 = h0 + 0.1f * (r2o[0] + h0);
        h1 = h1 + 0.1f * (r2o[1] + h1);
        V0[l]      = h0;
        V0[l + 64] = h1;
    }
    BARRIER();                                     // B12

    // -------- e1 on [hf, hf] (hf = h/256, exact pow2 scale after dot) --------
    dpart[t] = w_e1.dot_mask127(V0, t) * 0.00390625;
    BARRIER();                                     // B13
    if (w0) {
        float v[2];
#pragma unroll
        for (int i = 0; i < 2; ++i) {
            const int o = l + 64 * i;
            double ca = 0.0;
#pragma unroll
            for (int cc = 0; cc < 8; ++cc) ca += dpart[o + cc * HN];
            v[i] = fmaxf((float)ca + P[P_E1B + o], 0.0f);
        }
        double m, rs; w0_stats<2>(v, m, rs);
        const float eo0 = (float)(((double)v[0] - m) * rs) * P[P_EG + l] + P[P_EB + l];
        const float eo1 = (float)(((double)v[1] - m) * rs) * P[P_EG + l + 64] + P[P_EB + l + 64];
        // e2 head: fully in-wave (fast butterfly, same add order as r9)
        double p0 = (double)eo0 * (double)P[P_E2W + 2 * l];
        p0 = fma((double)eo1, (double)P[P_E2W + 2 * (l + 64)], p0);
        double p1 = (double)eo0 * (double)P[P_E2W + 2 * l + 1];
        p1 = fma((double)eo1, (double)P[P_E2W + 2 * (l + 64) + 1], p1);
        bfly_pair(p0, p1);
        if (l == 0) {
            out_logits[b * 2]     = (float)p0 + P[P_E2B];
            out_logits[b * 2 + 1] = (float)p1 + P[P_E2B + 1];
        }
    }
}

// ---------------- per-pair gumbel decisions + scatter ----------------
__device__ __forceinline__ int rowbase(int i) { return (i * (2 * NNODE - 1 - i)) >> 1; }

__global__ __launch_bounds__(256) void edges_kernel(const float* __restrict__ lg,
                                                    const float* __restrict__ tptr,
                                                    float* __restrict__ out)
{
    int q = blockIdx.x * blockDim.x + threadIdx.x;
    if (q >= NQ) return;
    // diagonal zeros (poison-safe: every output element is written each call)
    if (q < BN * NNODE) {
        int bb = q >> 8, ii = q & 255;
        out[(bb << 16) | (ii << 8) | ii] = 0.0f;
    }
    float temp = fminf(fmaxf(tptr[0], 0.1f), 2.0f);

    int b = q / NPAIR;
    int p = q - b * NPAIR;
    // decode (i,j): f32 estimate + exact integer fixups
    float discf = 261121.0f - 8.0f * (float)p;  // 511^2 - 8p (exact: < 2^24)
    int i = (int)((511.0f - sqrtf(discf)) * 0.5f);
    if (i < 0) i = 0;
    if (i > NNODE - 2) i = NNODE - 2;
    while (rowbase(i + 1) <= p) ++i;
    while (rowbase(i) > p) --i;
    int j = p - rowbase(i) + i + 1;

    uint32_t w0 = bits_partitionable((uint32_t)(2 * q));
    uint32_t w1 = bits_partitionable((uint32_t)(2 * q + 1));

    float u0 = bits_to_u(w0), u1 = bits_to_u(w1);
    float g0 = -logf(-logf(u0));     // f32 (reference computes f32 logs too)
    float g1 = -logf(-logf(u1));
    float l0 = lg[2 * b], l1 = lg[2 * b + 1];
    float A0 = (l0 + g0) / temp, A1 = (l1 + g1) / temp;
    float mx = fmaxf(A0, A1);
    float e0 = expf(A0 - mx), e1 = expf(A1 - mx);
    float ssum = e0 + e1;
    float y0 = e0 / ssum, y1 = e1 / ssum;
    float xe = (y0 >= y1) ? 1.0f : 0.0f;
    out[(b << 16) | (i << 8) | j] = xe;
    out[(b << 16) | (j << 8) | i] = xe;
}

extern "C" void kernel_launch(void* const* d_in, const int* in_sizes, int n_in,
                              void* d_out, int out_size, void* d_ws, size_t ws_size,
                              hipStream_t stream)
{
    const float* x    = (const float*)d_in[0];
    const float* st   = (const float*)d_in[1];
    const float* ipw  = (const float*)d_in[2];
    const float* ipb  = (const float*)d_in[3];
    const float* ipg  = (const float*)d_in[4];
    const float* ipbb = (const float*)d_in[5];
    const float* drw  = (const float*)d_in[6];
    const float* drb  = (const float*)d_in[7];
    const float* drg  = (const float*)d_in[8];
    const float* drbb = (const float*)d_in[9];
    const float* r1w  = (const float*)d_in[10];
    const float* r1b  = (const float*)d_in[11];
    const float* r2w  = (const float*)d_in[12];
    const float* r2b  = (const float*)d_in[13];
    const float* n1g  = (const float*)d_in[14];
    const float* n1b  = (const float*)d_in[15];
    const float* n2g  = (const float*)d_in[16];
    const float* n2b  = (const float*)d_in[17];
    // d_in[18] attn_w, d_in[19] attn_b: unused (softmax over identical nodes is uniform)
    const float* e1w  = (const float*)d_in[20];
    const float* e1b  = (const float*)d_in[21];
    const float* eg   = (const float*)d_in[22];
    const float* eb   = (const float*)d_in[23];
    const float* e2w  = (const float*)d_in[24];
    const float* e2b  = (const float*)d_in[25];
    const float* temp = (const float*)d_in[26];
    float* out = (float*)d_out;
    float* lg  = (float*)d_ws;   // 32 floats: per-batch logits

    hipLaunchKernelGGL(logits_kernel, dim3(BN), dim3(NT), 0, stream,
        x, st, ipw, ipb, ipg, ipbb, drw, drb, drg, drbb,
        r1w, r1b, r2w, r2b, n1g, n1b, n2g, n2b,
        e1w, e1b, eg, eb, e2w, e2b, lg);
    hipLaunchKernelGGL(edges_kernel, dim3((NQ + 255) / 256), dim3(256), 0, stream,
        lg, temp, out);
}

// Round 13
// 23.065 us; speedup vs baseline: 1.5232x; 1.0383x over previous
//
#include <hip/hip_runtime.h>
#include <stdint.h>
#include <math.h>

#define BN 16
#define LATN 64
#define STATSN 7
#define ZN 71
#define HN 128
#define H2N 256
#define NNODE 256
#define NPAIR 32640            // N*(N-1)/2
#define NQ 522240              // BN*NPAIR
#define NT 1024                // logits block size (16 waves)

// Raw barrier: drain LDS only (lgkmcnt); leave global prefetches in flight.
#define BARRIER() asm volatile("s_waitcnt lgkmcnt(0)\n\ts_barrier" ::: "memory")

// ---------------- Threefry-2x32, 20 rounds, key = (0, 42) ----------------
__device__ __forceinline__ void tf2x32(uint32_t x0, uint32_t x1,
                                       uint32_t& o0, uint32_t& o1) {
    const uint32_t ks0 = 0u, ks1 = 42u, ks2 = 0x1BD11BF0u;  // 0^42^0x1BD11BDA
    x0 += ks0; x1 += ks1;
#define TFRND(r) { x0 += x1; x1 = (x1 << (r)) | (x1 >> (32 - (r))); x1 ^= x0; }
    TFRND(13) TFRND(15) TFRND(26) TFRND(6)
    x0 += ks1; x1 += ks2 + 1u;
    TFRND(17) TFRND(29) TFRND(16) TFRND(24)
    x0 += ks2; x1 += ks0 + 2u;
    TFRND(13) TFRND(15) TFRND(26) TFRND(6)
    x0 += ks0; x1 += ks1 + 3u;
    TFRND(17) TFRND(29) TFRND(16) TFRND(24)
    x0 += ks1; x1 += ks2 + 4u;
    TFRND(13) TFRND(15) TFRND(26) TFRND(6)
    x0 += ks2; x1 += ks0 + 5u;
#undef TFRND
    o0 = x0; o1 = x1;
}

__device__ __forceinline__ uint32_t bits_partitionable(uint32_t m) {
    uint32_t o0, o1;
    tf2x32(0u, m, o0, o1);
    return o0 ^ o1;
}

__device__ __forceinline__ float bits_to_u(uint32_t w) {
    float f = __uint_as_float((w >> 9) | 0x3f800000u) - 1.0f;
    const float mn = 1e-9f;
    return fmaxf(mn, f * (1.0f - mn) + mn);
}

// ---------------- fast bit-exact 64-lane butterfly transport ----------------
// (r12-verified: value added is bitwise identical to __shfl_xor chain)
template<int CTRL>
__device__ __forceinline__ double dppd(double x) {
    int lo = __double2loint(x), hi = __double2hiint(x);
    lo = __builtin_amdgcn_update_dpp(0, lo, CTRL, 0xF, 0xF, true);
    hi = __builtin_amdgcn_update_dpp(0, hi, CTRL, 0xF, 0xF, true);
    return __hiloint2double(hi, lo);
}
__device__ __forceinline__ double swz16d(double x) {
    int lo = __double2loint(x), hi = __double2hiint(x);
    lo = __builtin_amdgcn_ds_swizzle(lo, 0x401F);
    hi = __builtin_amdgcn_ds_swizzle(hi, 0x401F);
    return __hiloint2double(hi, lo);
}
__device__ __forceinline__ void bfly_pair(double& a, double& q) {
    a += dppd<0xB1>(a);   q += dppd<0xB1>(q);    // xor1
    a += dppd<0x4E>(a);   q += dppd<0x4E>(q);    // xor2
    a += dppd<0x141>(a);  q += dppd<0x141>(q);   // xor4-equiv
    a += dppd<0x140>(a);  q += dppd<0x140>(q);   // xor8-equiv
    a += swz16d(a);       q += swz16d(q);        // xor16
    a += __shfl_xor(a, 32, 64);
    q += __shfl_xor(q, 32, 64);                  // xor32
}

// ---------------- register-resident weight slice (1024 threads) ----------------
// Activations now live in LDS as f64 (exact f32-rounded values) -> vin reads
// are contiguous f64 (b128-pairable) and need no per-element cvt.
template<int K, int O>
struct WS {
    static constexpr int C    = NT / O;      // 4 for O=256, 8 for O=128
    static constexpr int KC   = (K + C - 1) / C;
    static constexpr int LOGO = (O == 256) ? 8 : 7;
    float w[KC];
    __device__ __forceinline__ void load(const float* __restrict__ W, int t) {
        const int out = t & (O - 1);
        const int k0 = (t >> LOGO) * KC;
#pragma unroll
        for (int i = 0; i < KC; ++i) {
            const int k = k0 + i;
            w[i] = ((K % C == 0) || k < K) ? W[k * O + out] : 0.0f;
        }
    }
    // r3/r6-verified fma pairing; vin values bitwise-equal to (double)f32
    __device__ __forceinline__ double dot(const double* __restrict__ vin, int t) const {
        const int k0 = (t >> LOGO) * KC;
        double a0 = 0.0, a1 = 0.0;
#pragma unroll
        for (int i = 0; i < KC; i += 2) {
            a0 = fma(vin[k0 + i], (double)w[i], a0);
            if (i + 1 < KC) a1 = fma(vin[k0 + i + 1], (double)w[i + 1], a1);
        }
        return a0 + a1;
    }
    __device__ __forceinline__ double dot_mask127(const double* __restrict__ vin, int t) const {
        const int k0 = (t >> LOGO) * KC;
        double a0 = 0.0, a1 = 0.0;
#pragma unroll
        for (int i = 0; i < KC; i += 2) {
            a0 = fma(vin[(k0 + i) & 127], (double)w[i], a0);
            if (i + 1 < KC) a1 = fma(vin[(k0 + i + 1) & 127], (double)w[i + 1], a1);
        }
        return a0 + a1;
    }
};

// wave0 LN stats: fast butterfly; rsqrt = f32 seed + 2 f64 Newton (r8-verified)
template<int NV>
__device__ __forceinline__ void w0_stats(const float* v, double& m, double& rs) {
    double a = 0.0, q = 0.0;
#pragma unroll
    for (int i = 0; i < NV; ++i) {
        a += (double)v[i];
        q += (double)v[i] * (double)v[i];
    }
    bfly_pair(a, q);
    constexpr double O = (double)(NV * 64);
    m = a * (1.0 / O);
    const double d = q * (1.0 / O) - m * m + 1e-5;
    double r = (double)rsqrtf((float)d);
    r = r * (1.5 - 0.5 * d * r * r);
    r = r * (1.5 - 0.5 * d * r * r);
    rs = r;
}

// epilogue-parameter LDS layout (floats)
#define P_IPB   0
#define P_IPG   256
#define P_IPBB  512
#define P_DRB   768
#define P_DRG   896
#define P_DRBB  1024
#define P_R1B   1152   /* 256: both layers */
#define P_N1G   1408
#define P_N1B   1664
#define P_N2G   1920
#define P_N2B   2176
#define P_R2B   2432
#define P_E1B   2688
#define P_EG    2816
#define P_EB    2944
#define P_E2W   3072   /* 256 */
#define P_E2B   3328   /* 2 */
#define P_SIZE  3332

__global__ __launch_bounds__(NT, 1) void logits_kernel(
    const float* __restrict__ x, const float* __restrict__ st,
    const float* __restrict__ ipw, const float* __restrict__ ipb,
    const float* __restrict__ ipg, const float* __restrict__ ipbb,
    const float* __restrict__ drw, const float* __restrict__ drb,
    const float* __restrict__ drg, const float* __restrict__ drbb,
    const float* __restrict__ r1w, const float* __restrict__ r1b,
    const float* __restrict__ r2w, const float* __restrict__ r2b,
    const float* __restrict__ n1g, const float* __restrict__ n1b,
    const float* __restrict__ n2g, const float* __restrict__ n2b,
    const float* __restrict__ e1w, const float* __restrict__ e1b,
    const float* __restrict__ eg,  const float* __restrict__ eb,
    const float* __restrict__ e2w, const float* __restrict__ e2b,
    float* __restrict__ out_logits)
{
    __shared__ __align__(16) double V0[H2N];   // f64 holding exact f32 values
    __shared__ __align__(16) double V1[H2N];
    __shared__ double dpart[NT];
    __shared__ float P[P_SIZE];
    const int t = threadIdx.x;
    const int b = blockIdx.x;
    const int l = t & 63;
    const bool w0 = (t < 64);

    // weight slices, loads issued ~2 phases ahead of use
    WS<ZN, H2N> w_ip;
    WS<H2N, HN> w_dr;
    WS<HN, HN>  w_r1a, w_r2a, w_r1b, w_r2b;
    WS<H2N, HN> w_e1;

    // -------- prologue: params -> LDS, z -> V0, first two weight slices ------
    w_ip.load(ipw, t);
    w_dr.load(drw, t);
    if (t < 256) {
        P[P_IPB + t] = ipb[t];  P[P_IPG + t] = ipg[t];  P[P_IPBB + t] = ipbb[t];
        P[P_R1B + t] = r1b[t];  P[P_N1G + t] = n1g[t];  P[P_N1B + t] = n1b[t];
        P[P_N2G + t] = n2g[t];  P[P_N2B + t] = n2b[t];  P[P_R2B + t] = r2b[t];
        P[P_E2W + t] = e2w[t];
    } else if (t < 384) {
        const int i = t - 256;
        P[P_DRB + i] = drb[i];  P[P_DRG + i] = drg[i];  P[P_DRBB + i] = drbb[i];
        P[P_E1B + i] = e1b[i];  P[P_EG + i] = eg[i];    P[P_EB + i] = eb[i];
    } else if (t < 386) {
        P[P_E2B + (t - 384)] = e2b[t - 384];
    }
    if (t < LATN)      V0[t] = (double)x[b * LATN + t];          // exact widen
    else if (t < ZN)   V0[t] = (double)st[b * STATSN + (t - LATN)];
    else if (t < H2N)  V0[t] = 0.0;     // zero-pad so padded w entries hit 0
    BARRIER();                                     // B0

    float h0 = 0.0f, h1 = 0.0f;   // running h, wave0 regs only

    // -------- ip: [71]->relu->LN(256) -> V1 --------
    dpart[t] = w_ip.dot(V0, t);
    BARRIER();                                     // B1
    w_r1a.load(r1w, t);                            // prefetch (used B4-B5)
    if (w0) {
        float v[4];
#pragma unroll
        for (int i = 0; i < 4; ++i) {
            const int o = l + 64 * i;
            double ca = 0.0;
#pragma unroll
            for (int cc = 0; cc < 4; ++cc) ca += dpart[o + cc * H2N];
            v[i] = fmaxf((float)ca + P[P_IPB + o], 0.0f);
        }
        double m, rs; w0_stats<4>(v, m, rs);
#pragma unroll
        for (int i = 0; i < 4; ++i) {
            const int o = l + 64 * i;
            V1[o] = (double)((float)(((double)v[i] - m) * rs) * P[P_IPG + o] + P[P_IPBB + o]);
        }
    }
    BARRIER();                                     // B2

    // -------- dr: [256]->[128], relu, LN -> h (regs); fused LN1a -> V1 -------
    dpart[t] = w_dr.dot(V1, t);
    BARRIER();                                     // B3
    w_r2a.load(r2w, t);                            // prefetch (used B6-B7)
    if (w0) {
        float v[2];
#pragma unroll
        for (int i = 0; i < 2; ++i) {
            const int o = l + 64 * i;
            double ca = 0.0;
#pragma unroll
            for (int cc = 0; cc < 8; ++cc) ca += dpart[o + cc * HN];
            v[i] = fmaxf((float)ca + P[P_DRB + o], 0.0f);
        }
        double m, rs; w0_stats<2>(v, m, rs);
        h0 = (float)(((double)v[0] - m) * rs) * P[P_DRG + l] + P[P_DRBB + l];
        h1 = (float)(((double)v[1] - m) * rs) * P[P_DRG + l + 64] + P[P_DRBB + l + 64];
        float hv[2] = {h0, h1};
        double m1, rs1; w0_stats<2>(hv, m1, rs1);  // LN1a fused
        V1[l]      = (double)((float)(((double)h0 - m1) * rs1) * P[P_N1G + l] + P[P_N1B + l]);
        V1[l + 64] = (double)((float)(((double)h1 - m1) * rs1) * P[P_N1G + l + 64] + P[P_N1B + l + 64]);
    }
    BARRIER();                                     // B4

    // -------- res0 lin1 + relu + LN2 -> V1 --------
    dpart[t] = w_r1a.dot(V1, t);
    BARRIER();                                     // B5
    w_r1b.load(r1w + HN * HN, t);                  // prefetch (used B8-B9)
    if (w0) {
        float v[2];
#pragma unroll
        for (int i = 0; i < 2; ++i) {
            const int o = l + 64 * i;
            double ca = 0.0;
#pragma unroll
            for (int cc = 0; cc < 8; ++cc) ca += dpart[o + cc * HN];
            v[i] = fmaxf((float)ca + P[P_R1B + o], 0.0f);
        }
        double m, rs; w0_stats<2>(v, m, rs);
        V1[l]      = (double)((float)(((double)v[0] - m) * rs) * P[P_N2G + l] + P[P_N2B + l]);
        V1[l + 64] = (double)((float)(((double)v[1] - m) * rs) * P[P_N2G + l + 64] + P[P_N2B + l + 64]);
    }
    BARRIER();                                     // B6

    // -------- res0 lin2 + residual; fused LN1b -> V1 --------
    dpart[t] = w_r2a.dot(V1, t);
    BARRIER();                                     // B7
    w_r2b.load(r2w + HN * HN, t);                  // prefetch (used B10-B11)
    if (w0) {
        float r2o[2];
#pragma unroll
        for (int i = 0; i < 2; ++i) {
            const int o = l + 64 * i;
            double ca = 0.0;
#pragma unroll
            for (int cc = 0; cc < 8; ++cc) ca += dpart[o + cc * HN];
            r2o[i] = (float)ca + P[P_R2B + o];
        }
        h0 = h0 + 0.1f * (r2o[0] + h0);
        h1 = h1 + 0.1f * (r2o[1] + h1);
        float hv[2] = {h0, h1};
        double m1, rs1; w0_stats<2>(hv, m1, rs1);  // LN1b fused
        V1[l]      = (double)((float)(((double)h0 - m1) * rs1) * P[P_N1G + HN + l] + P[P_N1B + HN + l]);
        V1[l + 64] = (double)((float)(((double)h1 - m1) * rs1) * P[P_N1G + HN + l + 64] + P[P_N1B + HN + l + 64]);
    }
    BARRIER();                                     // B8

    // -------- res1 lin1 + relu + LN2 -> V1 --------
    dpart[t] = w_r1b.dot(V1, t);
    BARRIER();                                     // B9
    w_e1.load(e1w, t);                             // prefetch (used B12-B13)
    if (w0) {
        float v[2];
#pragma unroll
        for (int i = 0; i < 2; ++i) {
            const int o = l + 64 * i;
            double ca = 0.0;
#pragma unroll
            for (int cc = 0; cc < 8; ++cc) ca += dpart[o + cc * HN];
            v[i] = fmaxf((float)ca + P[P_R1B + HN + o], 0.0f);
        }
        double m, rs; w0_stats<2>(v, m, rs);
        V1[l]      = (double)((float)(((double)v[0] - m) * rs) * P[P_N2G + HN + l] + P[P_N2B + HN + l]);
        V1[l + 64] = (double)((float)(((double)v[1] - m) * rs) * P[P_N2G + HN + l + 64] + P[P_N2B + HN + l + 64]);
    }
    BARRIER();                                     // B10

    // -------- res1 lin2 + residual -> V0 (raw h; 1/256 applied in e1 dot) ----
    dpart[t] = w_r2b.dot(V1, t);
    BARRIER();                                     // B11
    if (w0) {
        float r2o[2];
#pragma unroll
        for (int i = 0; i < 2; ++i) {
            const int o = l + 64 * i;
            double ca = 0.0;
#pragma unroll
            for (int cc = 0; cc < 8; ++cc) ca += dpart[o + cc * HN];
            r2o[i] = (float)ca + P[P_R2B + HN + o];
        }
        h0 = h0 + 0.1f * (r2o[0] + h0);
        h1 = h1 + 0.1f * (r2o[1] + h1);
        V0[l]      = (double)h0;                   // exact widen
        V0[l + 64] = (double)h1;
    }
    BARRIER();                                     // B12

    // -------- e1 on [hf, hf] (hf = h/256, exact pow2 scale after dot) --------
    dpart[t] = w_e1.dot_mask127(V0, t) * 0.00390625;
    BARRIER();                                     // B13
    if (w0) {
        float v[2];
#pragma unroll
        for (int i = 0; i < 2; ++i) {
            const int o = l + 64 * i;
            double ca = 0.0;
#pragma unroll
            for (int cc = 0; cc < 8; ++cc) ca += dpart[o + cc * HN];
            v[i] = fmaxf((float)ca + P[P_E1B + o], 0.0f);
        }
        double m, rs; w0_stats<2>(v, m, rs);
        const float eo0 = (float)(((double)v[0] - m) * rs) * P[P_EG + l] + P[P_EB + l];
        const float eo1 = (float)(((double)v[1] - m) * rs) * P[P_EG + l + 64] + P[P_EB + l + 64];
        // e2 head: fully in-wave (fast butterfly, same add order as r9/r12)
        double p0 = (double)eo0 * (double)P[P_E2W + 2 * l];
        p0 = fma((double)eo1, (double)P[P_E2W + 2 * (l + 64)], p0);
        double p1 = (double)eo0 * (double)P[P_E2W + 2 * l + 1];
        p1 = fma((double)eo1, (double)P[P_E2W + 2 * (l + 64) + 1], p1);
        bfly_pair(p0, p1);
        if (l == 0) {
            out_logits[b * 2]     = (float)p0 + P[P_E2B];
            out_logits[b * 2 + 1] = (float)p1 + P[P_E2B + 1];
        }
    }
}

// ---------------- per-pair gumbel decisions + scatter ----------------
__device__ __forceinline__ int rowbase(int i) { return (i * (2 * NNODE - 1 - i)) >> 1; }

__global__ __launch_bounds__(256) void edges_kernel(const float* __restrict__ lg,
                                                    const float* __restrict__ tptr,
                                                    float* __restrict__ out)
{
    int q = blockIdx.x * blockDim.x + threadIdx.x;
    if (q >= NQ) return;
    // diagonal zeros (poison-safe: every output element is written each call)
    if (q < BN * NNODE) {
        int bb = q >> 8, ii = q & 255;
        out[(bb << 16) | (ii << 8) | ii] = 0.0f;
    }
    float temp = fminf(fmaxf(tptr[0], 0.1f), 2.0f);

    int b = q / NPAIR;
    int p = q - b * NPAIR;
    // decode (i,j): f32 estimate + exact integer fixups
    float discf = 261121.0f - 8.0f * (float)p;  // 511^2 - 8p (exact: < 2^24)
    int i = (int)((511.0f - sqrtf(discf)) * 0.5f);
    if (i < 0) i = 0;
    if (i > NNODE - 2) i = NNODE - 2;
    while (rowbase(i + 1) <= p) ++i;
    while (rowbase(i) > p) --i;
    int j = p - rowbase(i) + i + 1;

    uint32_t w0 = bits_partitionable((uint32_t)(2 * q));
    uint32_t w1 = bits_partitionable((uint32_t)(2 * q + 1));

    float u0 = bits_to_u(w0), u1 = bits_to_u(w1);
    float g0 = -logf(-logf(u0));     // f32 (r12-verified)
    float g1 = -logf(-logf(u1));
    float l0 = lg[2 * b], l1 = lg[2 * b + 1];
    float A0 = (l0 + g0) / temp, A1 = (l1 + g1) / temp;
    float mx = fmaxf(A0, A1);
    float e0 = expf(A0 - mx), e1 = expf(A1 - mx);
    float ssum = e0 + e1;
    float y0 = e0 / ssum, y1 = e1 / ssum;
    float xe = (y0 >= y1) ? 1.0f : 0.0f;
    out[(b << 16) | (i << 8) | j] = xe;
    out[(b << 16) | (j << 8) | i] = xe;
}

extern "C" void kernel_launch(void* const* d_in, const int* in_sizes, int n_in,
                              void* d_out, int out_size, void* d_ws, size_t ws_size,
                              hipStream_t stream)
{
    const float* x    = (const float*)d_in[0];
    const float* st   = (const float*)d_in[1];
    const float* ipw  = (const float*)d_in[2];
    const float* ipb  = (const float*)d_in[3];
    const float* ipg  = (const float*)d_in[4];
    const float* ipbb = (const float*)d_in[5];
    const float* drw  = (const float*)d_in[6];
    const float* drb  = (const float*)d_in[7];
    const float* drg  = (const float*)d_in[8];
    const float* drbb = (const float*)d_in[9];
    const float* r1w  = (const float*)d_in[10];
    const float* r1b  = (const float*)d_in[11];
    const float* r2w  = (const float*)d_in[12];
    const float* r2b  = (const float*)d_in[13];
    const float* n1g  = (const float*)d_in[14];
    const float* n1b  = (const float*)d_in[15];
    const float* n2g  = (const float*)d_in[16];
    const float* n2b  = (const float*)d_in[17];
    // d_in[18] attn_w, d_in[19] attn_b: unused (softmax over identical nodes is uniform)
    const float* e1w  = (const float*)d_in[20];
    const float* e1b  = (const float*)d_in[21];
    const float* eg   = (const float*)d_in[22];
    const float* eb   = (const float*)d_in[23];
    const float* e2w  = (const float*)d_in[24];
    const float* e2b  = (const float*)d_in[25];
    const float* temp = (const float*)d_in[26];
    float* out = (float*)d_out;
    float* lg  = (float*)d_ws;   // 32 floats: per-batch logits

    hipLaunchKernelGGL(logits_kernel, dim3(BN), dim3(NT), 0, stream,
        x, st, ipw, ipb, ipg, ipbb, drw, drb, drg, drbb,
        r1w, r1b, r2w, r2b, n1g, n1b, n2g, n2b,
        e1w, e1b, eg, eb, e2w, e2b, lg);
    hipLaunchKernelGGL(edges_kernel, dim3((NQ + 255) / 256), dim3(256), 0, stream,
        lg, temp, out);
}